// Round 8
// baseline (135.793 us; speedup 1.0000x reference)
//
#include <hip/hip_runtime.h>
#include <hip/hip_bf16.h>
#include <float.h>

// B=4096, D=512, N=8192, temp=0.5
#define BN_ 4096
#define DD  512
#define NN  8192
#define SCALE 2.0f   // 1/temperature
#define NBLK 1056    // sum over bi of ceil((bi+1)/2): paired lower-triangle tiles

typedef unsigned short u16;
typedef __attribute__((ext_vector_type(8))) short short8;   // 8 bf16 = 4 VGPRs
typedef __attribute__((ext_vector_type(4))) float floatx4;  // MFMA acc

struct alignas(8) U16x4 { u16 x, y, z, w; };

__device__ __forceinline__ u16 f2bf(float f) {
    union { float f; unsigned u; } c; c.f = f;
    unsigned u = c.u;
    unsigned r = (u + 0x7fffu + ((u >> 16) & 1u)) >> 16;   // RNE
    return (u16)r;
}

__device__ __forceinline__ void async_copy16(const u16* g, u16* l) {
    __builtin_amdgcn_global_load_lds(
        (const __attribute__((address_space(1))) void*)g,
        (__attribute__((address_space(3))) void*)l, 16, 0, 0);
}

// ------ kernel 1: fp32 -> bf16 concat + per-block positive-dot partial ------
// EXACT round-0 version.  Block 0 zero-inits d_out (harness poisons with 0xAA).
__global__ __launch_bounds__(256) void convert_pos_kernel(const float* __restrict__ hi,
                                                          const float* __restrict__ hj,
                                                          u16* __restrict__ H,
                                                          float* __restrict__ Pos,
                                                          float* __restrict__ out) {
    __shared__ float red[4];
    int t = blockIdx.x * 256 + threadIdx.x;     // 2048 blocks -> 524288 threads
    int e = t * 4;
    const int BD = BN_ * DD;
    float4 a = *(const float4*)(hi + e);
    float4 b = *(const float4*)(hj + e);
    U16x4 oa, ob;
    oa.x = f2bf(a.x); oa.y = f2bf(a.y); oa.z = f2bf(a.z); oa.w = f2bf(a.w);
    ob.x = f2bf(b.x); ob.y = f2bf(b.y); ob.z = f2bf(b.z); ob.w = f2bf(b.w);
    *(U16x4*)(H + e) = oa;
    *(U16x4*)(H + BD + e) = ob;
    float dot = a.x * b.x + a.y * b.y + a.z * b.z + a.w * b.w;
#pragma unroll
    for (int msk = 1; msk < 64; msk <<= 1) dot += __shfl_xor(dot, msk);
    int lane = threadIdx.x & 63, wid = threadIdx.x >> 6;
    if (lane == 0) red[wid] = dot;
    __syncthreads();
    if (threadIdx.x == 0) {
        Pos[blockIdx.x] = red[0] + red[1] + red[2] + red[3];
        if (blockIdx.x == 0) *out = 0.0f;
    }
}

// ------------- kernel 2: symmetric Gram, PAIRED lower-triangle 128x128 tiles -------------
// r7 falsifier: occupancy 33->52% did NOT help -> bound by per-CU shared traffic
// (LDS reads + L2/L3 staging service), not latency.  This round cuts bytes/FLOP:
// each block computes TWO tiles (bi,bj0),(bi,bj0+1) sharing the staged A panel.
//  - 8 waves = 2 sub-tiles x (2x2 of 64x64): r0's exact per-wave profile
//    (acc[4][4]=64 AGPR, 16 KB LDS read/wave/K-step, minimal 2x2 duplication).
//  - global staging 532 -> 405 MB; FLOP per K-step-slot per CU doubles.
//  - LDS 48 KB (A + B0 + B1), single-buffered, same 2-barrier K-loop.
//  - regs ~50 arch + 64 acc <= 128 -> __launch_bounds__(512,4) -> 2 blocks/CU.
// Even-bi rows end in a diagonal singleton: bj1==bj0, sub-1 writes suppressed.
#define CUM(b) (((b) & 1) ? (((b) + 1) * ((b) + 1) / 4) : ((b) * ((b) + 2) / 4))

__global__ __launch_bounds__(512, 4) void gram_kernel(const u16* __restrict__ H,
                                                      float* __restrict__ Mpart,
                                                      float* __restrict__ Spart) {
    __shared__ u16 As[128 * 64];        // 16 KB, shared by both sub-tiles
    __shared__ u16 Bs[2][128 * 64];     // 32 KB   (total 48 KB)

    // epilogue scratch aliases onto As (after K-loop's final barrier): 8 KB used
    float* Rm = (float*)&As[0];          // [sub:2][wc:2][128]
    float* Rs = Rm + 512;
    float* Cm = Rs + 512;                // [sub:2][wr:2][128]
    float* Cs = Cm + 512;

    const int tid  = threadIdx.x;
    const int lane = tid & 63;
    const int wid  = tid >> 6;        // 0..7
    const int quad = lane >> 4;
    const int ln15 = lane & 15;
    const int sub  = wid >> 2;        // 0..1 : which sub-tile this wave works
    const int wr = (wid >> 1) & 1;    // 2x2 within the sub-tile
    const int wc = wid & 1;

    // bijective XCD swizzle (1056 = 8*132)
    int p = ((int)blockIdx.x & 7) * (NBLK / 8) + ((int)blockIdx.x >> 3);

    // decode (bi, pair q): cum(bi) pairs precede row bi
    int bi = (int)(2.0f * sqrtf((float)p + 1.0f));
    if (bi > 63) bi = 63;
    while (CUM(bi + 1) <= p) bi++;
    while (CUM(bi) > p) bi--;
    const int q   = p - CUM(bi);
    const int bj0 = 2 * q;
    const int bj1 = (bj0 + 1 <= bi) ? bj0 + 1 : bj0;   // singleton on even-bi diag
    const bool single = (bj1 == bj0);
    const int biBase = bi * 128;
    const int bjS = sub ? bj1 : bj0;                   // this wave's sub-tile col
    const bool diagS = (bjS == bi);

    // staging: A = 1024 chunks, B0/B1 = 1024 each; 512 threads x 6 copies.
    // chunk c = j*512+tid: row = j*64 + (tid>>3); (j*64)&7==0 -> swizzled k-slot
    // j-independent -> one per-thread source base + uniform (SGPR) strides.
    const int rowT = tid >> 3;                           // 0..63
    const int kcT  = ((tid & 7) ^ (rowT & 7)) * 8;       // source-side swizzle
    const u16* __restrict__ src = H + (size_t)(biBase + rowT) * DD + kcT;
    const ptrdiff_t dB0 = (ptrdiff_t)(bj0 * 128 - biBase) * DD;
    const ptrdiff_t dB1 = (ptrdiff_t)(bj1 * 128 - biBase) * DD;
    const ptrdiff_t dJ  = (ptrdiff_t)64 * DD;            // 64-row j-stride
    const int d0 = tid * 8;                              // LDS dest (elements)

    floatx4 acc[4][4];
#pragma unroll
    for (int i = 0; i < 4; i++)
#pragma unroll
        for (int j = 0; j < 4; j++) acc[i][j] = (floatx4)0.0f;

    for (int k0 = 0; k0 < DD; k0 += 64) {
        async_copy16(src + k0,            &As[d0]);
        async_copy16(src + dJ + k0,       &As[d0 + 4096]);
        async_copy16(src + dB0 + k0,      &Bs[0][d0]);
        async_copy16(src + dB0 + dJ + k0, &Bs[0][d0 + 4096]);
        async_copy16(src + dB1 + k0,      &Bs[1][d0]);
        async_copy16(src + dB1 + dJ + k0, &Bs[1][d0 + 4096]);
        __syncthreads();

        const u16* __restrict__ Bsub = Bs[sub];
#pragma unroll
        for (int kk = 0; kk < 2; kk++) {
            int ck = kk * 4 + quad;     // K-chunk 0..7 within the 64-wide tile
            short8 b[4];
#pragma unroll
            for (int tn = 0; tn < 4; tn++) {
                int r = wc * 64 + tn * 16 + ln15;
                b[tn] = *(const short8*)&Bsub[(r * 8 + (ck ^ (r & 7))) * 8];
            }
#pragma unroll
            for (int tm = 0; tm < 4; tm++) {
                int r = wr * 64 + tm * 16 + ln15;
                short8 a = *(const short8*)&As[(r * 8 + (ck ^ (r & 7))) * 8];
#pragma unroll
                for (int tn = 0; tn < 4; tn++)
                    acc[tm][tn] = __builtin_amdgcn_mfma_f32_16x16x32_bf16(
                        a, b[tn], acc[tm][tn], 0, 0, 0);
            }
        }
        __syncthreads();
    }

    // scale in place; mask self-similarity on diagonal sub-tiles
    // C/D layout: local row = wr*64 + tm*16 + quad*4 + reg, col = wc*64 + tn*16 + ln15
#pragma unroll
    for (int tm = 0; tm < 4; tm++)
#pragma unroll
        for (int tn = 0; tn < 4; tn++)
#pragma unroll
            for (int r = 0; r < 4; r++) {
                float v = SCALE * acc[tm][tn][r];
                if (diagS) {
                    int lrow = wr * 64 + tm * 16 + quad * 4 + r;
                    int lcol = wc * 64 + tn * 16 + ln15;
                    if (lrow == lcol) v = -FLT_MAX;
                }
                acc[tm][tn][r] = v;
            }

    // row pass: per-row max+sumexp over this wave's 64 cols
#pragma unroll
    for (int tm = 0; tm < 4; tm++) {
#pragma unroll
        for (int r = 0; r < 4; r++) {
            float vmax = -FLT_MAX;
#pragma unroll
            for (int tn = 0; tn < 4; tn++) vmax = fmaxf(vmax, acc[tm][tn][r]);
#pragma unroll
            for (int msk = 1; msk < 16; msk <<= 1)
                vmax = fmaxf(vmax, __shfl_xor(vmax, msk));
            float s = 0.0f;
#pragma unroll
            for (int tn = 0; tn < 4; tn++) s += __expf(acc[tm][tn][r] - vmax);
#pragma unroll
            for (int msk = 1; msk < 16; msk <<= 1) s += __shfl_xor(s, msk);
            if (ln15 == 0) {
                int x = wr * 64 + tm * 16 + quad * 4 + r;
                Rm[sub * 256 + wc * 128 + x] = vmax;
                Rs[sub * 256 + wc * 128 + x] = s;
            }
        }
    }

    // col pass (transpose tile): per-col max+sumexp over this wave's 64 rows
    if (!diagS) {
#pragma unroll
        for (int tn = 0; tn < 4; tn++) {
            float cm = -FLT_MAX;
#pragma unroll
            for (int tm = 0; tm < 4; tm++)
#pragma unroll
                for (int r = 0; r < 4; r++) cm = fmaxf(cm, acc[tm][tn][r]);
            cm = fmaxf(cm, __shfl_xor(cm, 16));
            cm = fmaxf(cm, __shfl_xor(cm, 32));
            float s = 0.0f;
#pragma unroll
            for (int tm = 0; tm < 4; tm++)
#pragma unroll
                for (int r = 0; r < 4; r++) s += __expf(acc[tm][tn][r] - cm);
            s += __shfl_xor(s, 16);
            s += __shfl_xor(s, 32);
            if (quad == 0) {
                int y = wc * 64 + tn * 16 + ln15;
                Cm[sub * 256 + wr * 128 + y] = cm;
                Cs[sub * 256 + wr * 128 + y] = s;
            }
        }
    }
    __syncthreads();

    // merge wave halves; write slot-major partials Mpart[slot*NN + globalRow].
    // 4 segments of 128 threads: {sub0 rows, sub0 cols, sub1 rows, sub1 cols}.
    const int r5 = tid & 127;
    const int seg = tid >> 7;
    if (seg == 0) {
        float m0 = Rm[r5], m1 = Rm[128 + r5];
        float mm = fmaxf(m0, m1);
        float s = Rs[r5] * __expf(m0 - mm) + Rs[128 + r5] * __expf(m1 - mm);
        Mpart[(size_t)bj0 * NN + biBase + r5] = mm;
        Spart[(size_t)bj0 * NN + biBase + r5] = s;
    } else if (seg == 1) {
        if (bj0 != bi) {
            float m0 = Cm[r5], m1 = Cm[128 + r5];
            float mm = fmaxf(m0, m1);
            float s = Cs[r5] * __expf(m0 - mm) + Cs[128 + r5] * __expf(m1 - mm);
            Mpart[(size_t)bi * NN + bj0 * 128 + r5] = mm;
            Spart[(size_t)bi * NN + bj0 * 128 + r5] = s;
        }
    } else if (seg == 2) {
        if (!single) {
            float m0 = Rm[256 + r5], m1 = Rm[384 + r5];
            float mm = fmaxf(m0, m1);
            float s = Rs[256 + r5] * __expf(m0 - mm) + Rs[384 + r5] * __expf(m1 - mm);
            Mpart[(size_t)bj1 * NN + biBase + r5] = mm;
            Spart[(size_t)bj1 * NN + biBase + r5] = s;
        }
    } else {
        if (!single && bj1 != bi) {
            float m0 = Cm[256 + r5], m1 = Cm[384 + r5];
            float mm = fmaxf(m0, m1);
            float s = Cs[256 + r5] * __expf(m0 - mm) + Cs[384 + r5] * __expf(m1 - mm);
            Mpart[(size_t)bi * NN + bj1 * 128 + r5] = mm;
            Spart[(size_t)bi * NN + bj1 * 128 + r5] = s;
        }
    }
}

// ------ kernel 3: combine 64 slot-partials per row + pos partials -> loss ------
// 128 blocks x 64 rows; each wave covers 16 slots of its 64 rows, merged in LDS.
__global__ __launch_bounds__(256) void lse_kernel(const float* __restrict__ Mpart,
                                                  const float* __restrict__ Spart,
                                                  const float* __restrict__ Pos,
                                                  float* __restrict__ out) {
    __shared__ float sm[4][64], ss[4][64];
    __shared__ float red[256];
    int tid = threadIdx.x;
    int wid = tid >> 6, lane = tid & 63;
    int r = blockIdx.x * 64 + lane;
    float m = -FLT_MAX, s = 0.0f;
#pragma unroll
    for (int i = 0; i < 16; i++) {
        int c = wid * 16 + i;
        float mc = Mpart[(size_t)c * NN + r];   // coalesced: lane-stride 4B
        float sc = Spart[(size_t)c * NN + r];
        float mn = fmaxf(m, mc);
        s = s * __expf(m - mn) + sc * __expf(mc - mn);
        m = mn;
    }
    sm[wid][lane] = m; ss[wid][lane] = s;
    __syncthreads();
    float v = 0.0f;
    if (tid < 64) {
        float m0 = sm[0][tid], m1 = sm[1][tid], m2 = sm[2][tid], m3 = sm[3][tid];
        float mm = fmaxf(fmaxf(m0, m1), fmaxf(m2, m3));
        float sa = ss[0][tid] * __expf(m0 - mm) + ss[1][tid] * __expf(m1 - mm)
                 + ss[2][tid] * __expf(m2 - mm) + ss[3][tid] * __expf(m3 - mm);
        v = mm + logf(sa);
        // 2048 convert-block partials; this block's share is 16 of them
        if (tid < 16) v += -4.0f * Pos[blockIdx.x * 16 + tid];
    }
    red[tid] = v;
    __syncthreads();
    for (int st = 128; st > 0; st >>= 1) {
        if (tid < st) red[tid] += red[tid + st];
        __syncthreads();
    }
    if (tid == 0) atomicAdd(out, red[0] * (1.0f / (float)NN));
}

extern "C" void kernel_launch(void* const* d_in, const int* in_sizes, int n_in,
                              void* d_out, int out_size, void* d_ws, size_t ws_size,
                              hipStream_t stream) {
    const float* hi = (const float*)d_in[0];
    const float* hj = (const float*)d_in[1];
    float* out = (float*)d_out;

    u16*   H     = (u16*)d_ws;                                            // 8 MB
    float* Mpart = (float*)((char*)d_ws + (size_t)8 * 1024 * 1024);       // 2 MB
    float* Spart = (float*)((char*)d_ws + (size_t)10 * 1024 * 1024);      // 2 MB
    float* Pos   = (float*)((char*)d_ws + (size_t)12 * 1024 * 1024);      // 8 KB

    convert_pos_kernel<<<2048, 256, 0, stream>>>(hi, hj, H, Pos, out);

    gram_kernel<<<NBLK, 512, 0, stream>>>(H, Mpart, Spart);

    lse_kernel<<<128, 256, 0, stream>>>(Mpart, Spart, Pos, out);
}